// Round 3
// baseline (282.905 us; speedup 1.0000x reference)
//
#include <hip/hip_runtime.h>
#include <stdint.h>

#define NB 16
#define NPIX 262144            // 512*512
#define K_RANK 104856u         // int(512*512*0.4 - 1)
#define NB1 4096
#define CAP 65536              // 256 chunks * 256 candidate slots per batch
#define SENT 0xFFFFFFFFu
#define PAD(i) ((i) + ((i) >> 4))

// Shared scan over 4096 padded counts in sh[]; the single thread whose range
// contains rank r writes digit + residual rank to the out pointers (shared).
__device__ inline void scan4096(const unsigned* __restrict__ sh, unsigned* wave_sums,
                                int tid, unsigned r,
                                unsigned* out_digit, unsigned* out_res) {
    unsigned sum = 0;
    #pragma unroll
    for (int j = 0; j < 16; ++j) sum += sh[tid * 17 + j];
    unsigned inc = sum;
    for (int off = 1; off < 64; off <<= 1) {
        unsigned v = __shfl_up(inc, off);
        if ((tid & 63) >= off) inc += v;
    }
    if ((tid & 63) == 63) wave_sums[tid >> 6] = inc;
    __syncthreads();
    unsigned woff = 0;
    for (int w = 0; w < (tid >> 6); ++w) woff += wave_sums[w];
    const unsigned excl = woff + inc - sum;
    if (r >= excl && r < excl + sum) {            // exactly one thread
        unsigned cum = excl;
        unsigned d   = (unsigned)(tid * 16);
        #pragma unroll
        for (int j = 0; j < 16; ++j) {
            unsigned c = sh[tid * 17 + j];
            if (cum + c > r) { d = (unsigned)(tid * 16 + j); break; }
            cum += c;
        }
        *out_digit = d;
        *out_res   = r - cum;
    }
}

// ---------------- K1: gray + histogram on float bits[31:20] + zero accum ----------------
__global__ void k_hist(const float* __restrict__ yp, unsigned* __restrict__ hist1,
                       unsigned* __restrict__ zr, int zcount) {
    __shared__ unsigned h[NB1];
    const int tid = threadIdx.x;
    const int gtid = blockIdx.x * 256 + tid;
    if (gtid < zcount) zr[gtid] = 0;   // zero accum (consumed only by later kernels)
    for (int i = tid; i < NB1; i += 256) h[i] = 0;
    __syncthreads();

    const int blk   = blockIdx.x;      // 4096 blocks, 256 per batch
    const int b     = blk >> 8;
    const int chunk = blk & 255;
    const long base = (long)b * 3 * NPIX;
    const int  o    = (chunk * 256 + tid) * 4;

    const float4 c0 = *(const float4*)(yp + base + o);
    const float4 c1 = *(const float4*)(yp + base + NPIX + o);
    const float4 c2 = *(const float4*)(yp + base + 2 * NPIX + o);

    atomicAdd(&h[__float_as_uint((c0.x + c1.x + c2.x) / 3.0f) >> 20], 1u);
    atomicAdd(&h[__float_as_uint((c0.y + c1.y + c2.y) / 3.0f) >> 20], 1u);
    atomicAdd(&h[__float_as_uint((c0.z + c1.z + c2.z) / 3.0f) >> 20], 1u);
    atomicAdd(&h[__float_as_uint((c0.w + c1.w + c2.w) / 3.0f) >> 20], 1u);
    __syncthreads();

    unsigned* gh = hist1 + b * NB1;
    for (int i = tid; i < NB1; i += 256) {
        unsigned v = h[i];
        if (v) atomicAdd(&gh[i], v);   // non-returning; only ~50 bins nonzero
    }
}

// ---------------- K2: fused loss + candidate collection ----------------
// Per-block redundant scan1 (hist1 is L2-resident) gives sel. Weight is fully
// determined by bin<sel / bin>sel for all pixels outside the selected bin:
//   w = 0.8 for bin<sel, 0.2 otherwise; sel-bin pixels get 0.2 here and the
// masked ones get the remaining 0.6*d added by k_sel from the (u,d) pairs.
__global__ void k_main(const float* __restrict__ yp, const float* __restrict__ yt,
                       const unsigned* __restrict__ hist1,
                       uint2* __restrict__ cand, double* __restrict__ accum) {
    __shared__ unsigned sh[NB1 + (NB1 >> 4)];
    __shared__ unsigned wave_sums[4];
    __shared__ unsigned s_sel, s_res;
    __shared__ unsigned cnt;
    __shared__ uint2 buf[1024];
    __shared__ float wsum[4];
    const int tid   = threadIdx.x;
    const int blk   = blockIdx.x;
    const int b     = blk >> 8;
    const int chunk = blk & 255;
    if (tid == 0) cnt = 0;

    const long base = (long)b * 3 * NPIX;
    const int  o    = (chunk * 256 + tid) * 4;

    // issue all heavy loads early; scan1 runs under their latency
    float4 p0 = *(const float4*)(yp + base + o);
    float4 p1 = *(const float4*)(yp + base + NPIX + o);
    float4 p2 = *(const float4*)(yp + base + 2 * NPIX + o);
    float4 t0 = *(const float4*)(yt + base + o);
    float4 t1 = *(const float4*)(yt + base + NPIX + o);
    float4 t2 = *(const float4*)(yt + base + 2 * NPIX + o);

    // ---- scan1 over hist1[b] ----
    const unsigned* hb = hist1 + b * NB1;
    for (int i = tid; i < NB1; i += 256) sh[PAD(i)] = hb[i];
    __syncthreads();
    scan4096(sh, wave_sums, tid, K_RANK, &s_sel, &s_res);
    __syncthreads();
    const unsigned sel = s_sel;

    // ---- loss body + candidate collect ----
    float s = 0.0f;
    {
        float g = (p0.x + p1.x + p2.x) / 3.0f;
        unsigned u = __float_as_uint(g);
        float d = fabsf(p0.x - t0.x) + fabsf(p1.x - t1.x) + fabsf(p2.x - t2.x);
        unsigned bin = u >> 20;
        s += ((bin < sel) ? 0.8f : 0.2f) * d;
        if (bin == sel) { unsigned i = atomicAdd(&cnt, 1u); buf[i] = make_uint2(u, __float_as_uint(d)); }
    }
    {
        float g = (p0.y + p1.y + p2.y) / 3.0f;
        unsigned u = __float_as_uint(g);
        float d = fabsf(p0.y - t0.y) + fabsf(p1.y - t1.y) + fabsf(p2.y - t2.y);
        unsigned bin = u >> 20;
        s += ((bin < sel) ? 0.8f : 0.2f) * d;
        if (bin == sel) { unsigned i = atomicAdd(&cnt, 1u); buf[i] = make_uint2(u, __float_as_uint(d)); }
    }
    {
        float g = (p0.z + p1.z + p2.z) / 3.0f;
        unsigned u = __float_as_uint(g);
        float d = fabsf(p0.z - t0.z) + fabsf(p1.z - t1.z) + fabsf(p2.z - t2.z);
        unsigned bin = u >> 20;
        s += ((bin < sel) ? 0.8f : 0.2f) * d;
        if (bin == sel) { unsigned i = atomicAdd(&cnt, 1u); buf[i] = make_uint2(u, __float_as_uint(d)); }
    }
    {
        float g = (p0.w + p1.w + p2.w) / 3.0f;
        unsigned u = __float_as_uint(g);
        float d = fabsf(p0.w - t0.w) + fabsf(p1.w - t1.w) + fabsf(p2.w - t2.w);
        unsigned bin = u >> 20;
        s += ((bin < sel) ? 0.8f : 0.2f) * d;
        if (bin == sel) { unsigned i = atomicAdd(&cnt, 1u); buf[i] = make_uint2(u, __float_as_uint(d)); }
    }
    __syncthreads();

    // write fixed candidate slots (SENT-padded; cap 256/chunk like prior rounds)
    const unsigned n = (cnt < 256u) ? cnt : 256u;
    uint2 v = make_uint2(SENT, 0u);
    if ((unsigned)tid < n) v = buf[tid];
    cand[(long)b * CAP + chunk * 256 + tid] = v;

    // block sum -> accum
    for (int off = 32; off > 0; off >>= 1) s += __shfl_down(s, off);
    if ((tid & 63) == 0) wsum[tid >> 6] = s;
    __syncthreads();
    if (tid == 0) {
        float tot = wsum[0] + wsum[1] + wsum[2] + wsum[3];
        atomicAdd(&accum[(blk & 63) * 16], (double)tot);   // 64 cache-line-spread slots
    }
}

// ---------------- K3: resolve low 20 threshold bits over candidates, add 0.6*masked-d ----------------
// One block per batch. Candidates (u,d): all pixels whose top-12 bin == sel.
__global__ void k_sel(const uint2* __restrict__ cand, const unsigned* __restrict__ hist1,
                      double* __restrict__ accum) {
    __shared__ unsigned sh[NB1 + (NB1 >> 4)];
    __shared__ float    sd[NB1 + (NB1 >> 4)];
    __shared__ unsigned h3[256];
    __shared__ float    sd3[256];
    __shared__ unsigned wave_sums[4];
    __shared__ unsigned s_sel, s_r2, s_bin2, s_r3, s_low;
    __shared__ float red[4];
    const int tid = threadIdx.x;
    const int b   = blockIdx.x;

    if (tid == 0) { s_bin2 = 0; s_r3 = 0; s_low = 0; }

    // ---- scan1 of hist1[b] -> sel, r2 (residual rank within sel bin) ----
    const unsigned* hb = hist1 + b * NB1;
    for (int i = tid; i < NB1; i += 256) sh[PAD(i)] = hb[i];
    __syncthreads();
    scan4096(sh, wave_sums, tid, K_RANK, &s_sel, &s_r2);
    __syncthreads();
    const unsigned r2 = s_r2;

    // ---- zero hist2/sumd, h3/sd3 ----
    for (int i = tid; i < NB1; i += 256) { sh[PAD(i)] = 0u; sd[PAD(i)] = 0.0f; }
    h3[tid] = 0u; sd3[tid] = 0.0f;
    __syncthreads();

    // ---- pass 1: histogram candidates on bits[19:8] with per-bin d sums ----
    const uint2* cb = cand + (long)b * CAP;
    for (int i = tid; i < CAP; i += 256) {
        uint2 v = cb[i];
        if (v.x != SENT) {
            unsigned bin = (v.x >> 8) & 0xFFFu;
            atomicAdd(&sh[PAD(bin)], 1u);
            atomicAdd(&sd[PAD(bin)], __uint_as_float(v.y));
        }
    }
    __syncthreads();

    // ---- scan2 -> bin2 (bits 19:8), r3 ----
    scan4096(sh, wave_sums, tid, r2, &s_bin2, &s_r3);
    __syncthreads();
    const unsigned bin2 = s_bin2;
    const unsigned r3   = s_r3;

    // ---- S_pre = sum of d over candidate bins strictly below bin2 ----
    float lp = 0.0f;
    #pragma unroll
    for (int j = 0; j < 16; ++j) {
        unsigned gb = (unsigned)(tid * 16 + j);
        if (gb < bin2) lp += sd[tid * 17 + j];
    }
    for (int off = 32; off > 0; off >>= 1) lp += __shfl_down(lp, off);
    if ((tid & 63) == 0) red[tid >> 6] = lp;
    __syncthreads();
    const float S_pre = red[0] + red[1] + red[2] + red[3];
    __syncthreads();

    // ---- pass 2: final byte histogram within bin2, with d sums ----
    for (int i = tid; i < CAP; i += 256) {
        uint2 v = cb[i];
        if (v.x != SENT && ((v.x >> 8) & 0xFFFu) == bin2) {
            atomicAdd(&h3[v.x & 0xFFu], 1u);
            atomicAdd(&sd3[v.x & 0xFFu], __uint_as_float(v.y));
        }
    }
    __syncthreads();

    // ---- scan3: 256 bins, one per thread -> low byte of threshold ----
    const unsigned sum = h3[tid];
    unsigned inc = sum;
    for (int off = 1; off < 64; off <<= 1) {
        unsigned v = __shfl_up(inc, off);
        if ((tid & 63) >= off) inc += v;
    }
    if ((tid & 63) == 63) wave_sums[tid >> 6] = inc;
    __syncthreads();
    unsigned woff = 0;
    for (int w = 0; w < (tid >> 6); ++w) woff += wave_sums[w];
    const unsigned excl = woff + inc - sum;
    if (sum > 0 && r3 >= excl && r3 < excl + sum) s_low = (unsigned)tid;
    __syncthreads();
    const unsigned low = s_low;

    // ---- S_b2 = sum of d over bin2 candidates with low byte <= low ----
    float l2 = ((unsigned)tid <= low) ? sd3[tid] : 0.0f;
    for (int off = 32; off > 0; off >>= 1) l2 += __shfl_down(l2, off);
    if ((tid & 63) == 0) red[tid >> 6] = l2;
    __syncthreads();
    if (tid == 0) {
        float S_b2 = red[0] + red[1] + red[2] + red[3];
        atomicAdd(&accum[(b & 63) * 16], 0.6 * ((double)S_pre + (double)S_b2));
    }
}

__global__ void k_final(const double* __restrict__ accum, float* __restrict__ out) {
    const int tid = threadIdx.x;      // 64 threads
    double v = accum[tid * 16];
    for (int off = 32; off > 0; off >>= 1) v += __shfl_down(v, off);
    if (tid == 0) out[0] = (float)(v / 12582912.0);   // 16*3*512*512
}

extern "C" void kernel_launch(void* const* d_in, const int* in_sizes, int n_in,
                              void* d_out, int out_size, void* d_ws, size_t ws_size,
                              hipStream_t stream) {
    const float* yt = (const float*)d_in[0];   // y_true
    const float* yp = (const float*)d_in[1];   // y_pred
    float* out = (float*)d_out;
    char* ws = (char*)d_ws;

    // ws layout
    unsigned* hist1 = (unsigned*)(ws);               // 262144 B (memset)
    double*   accum = (double*)(ws + 262144);        // 8192 B (zeroed by k_hist zr path)
    unsigned* zr    = (unsigned*)(ws + 262144);
    uint2*    cand  = (uint2*)(ws + (1 << 20));      // 16 * 65536 * 8 = 8 MB
    const int zcount = 8192 / 4;                     // 2048 words (accum)

    hipMemsetAsync(hist1, 0, 262144, stream);        // hist1 only

    k_hist <<<4096, 256, 0, stream>>>(yp, hist1, zr, zcount);
    k_main <<<4096, 256, 0, stream>>>(yp, yt, hist1, cand, accum);
    k_sel  <<<NB,   256, 0, stream>>>(cand, hist1, accum);
    k_final<<<1,    64,  0, stream>>>(accum, out);
}

// Round 4
// 204.059 us; speedup vs baseline: 1.3864x; 1.3864x over previous
//
#include <hip/hip_runtime.h>
#include <stdint.h>

#define NB 16
#define NPIX 262144            // 512*512
#define K_RANK 104856u         // int(512*512*0.4 - 1)
#define NB1 4096
#define CAP 262144             // per-batch candidate capacity (compacted; worst case NPIX)
#define PAD(i) ((i) + ((i) >> 4))

// Shared scan over 4096 padded counts in sh[]; the single thread whose range
// contains rank r writes digit + residual rank to the out pointers (shared).
__device__ inline void scan4096(const unsigned* __restrict__ sh, unsigned* wave_sums,
                                int tid, unsigned r,
                                unsigned* out_digit, unsigned* out_res) {
    unsigned sum = 0;
    #pragma unroll
    for (int j = 0; j < 16; ++j) sum += sh[tid * 17 + j];
    unsigned inc = sum;
    for (int off = 1; off < 64; off <<= 1) {
        unsigned v = __shfl_up(inc, off);
        if ((tid & 63) >= off) inc += v;
    }
    if ((tid & 63) == 63) wave_sums[tid >> 6] = inc;
    __syncthreads();
    unsigned woff = 0;
    for (int w = 0; w < (tid >> 6); ++w) woff += wave_sums[w];
    const unsigned excl = woff + inc - sum;
    if (r >= excl && r < excl + sum) {            // exactly one thread
        unsigned cum = excl;
        unsigned d   = (unsigned)(tid * 16);
        #pragma unroll
        for (int j = 0; j < 16; ++j) {
            unsigned c = sh[tid * 17 + j];
            if (cum + c > r) { d = (unsigned)(tid * 16 + j); break; }
            cum += c;
        }
        *out_digit = d;
        *out_res   = r - cum;
    }
}

// ---------------- K1: gray + histogram on float bits[31:20] + zero accum/ccnt ----------------
__global__ void k_hist(const float* __restrict__ yp, unsigned* __restrict__ hist1,
                       unsigned* __restrict__ zr, int zcount) {
    __shared__ unsigned h[NB1];
    const int tid = threadIdx.x;
    const int gtid = blockIdx.x * 256 + tid;
    if (gtid < zcount) zr[gtid] = 0;   // zero accum + ccnt (consumed only by later kernels)
    for (int i = tid; i < NB1; i += 256) h[i] = 0;
    __syncthreads();

    const int blk   = blockIdx.x;      // 4096 blocks, 256 per batch
    const int b     = blk >> 8;
    const int chunk = blk & 255;
    const long base = (long)b * 3 * NPIX;
    const int  o    = (chunk * 256 + tid) * 4;

    const float4 c0 = *(const float4*)(yp + base + o);
    const float4 c1 = *(const float4*)(yp + base + NPIX + o);
    const float4 c2 = *(const float4*)(yp + base + 2 * NPIX + o);

    atomicAdd(&h[__float_as_uint((c0.x + c1.x + c2.x) / 3.0f) >> 20], 1u);
    atomicAdd(&h[__float_as_uint((c0.y + c1.y + c2.y) / 3.0f) >> 20], 1u);
    atomicAdd(&h[__float_as_uint((c0.z + c1.z + c2.z) / 3.0f) >> 20], 1u);
    atomicAdd(&h[__float_as_uint((c0.w + c1.w + c2.w) / 3.0f) >> 20], 1u);
    __syncthreads();

    unsigned* gh = hist1 + b * NB1;
    for (int i = tid; i < NB1; i += 256) {
        unsigned v = h[i];
        if (v) atomicAdd(&gh[i], v);   // non-returning; only ~50 bins nonzero
    }
}

// ---------------- K2: fused loss + COMPACTED candidate collection ----------------
// Per-block redundant scan1 (hist1 is L2-resident) gives sel. Pixels outside the
// selected bin are fully weighted here (0.8 below / 0.2 above); sel-bin pixels get
// 0.2 here, and k_sel adds the remaining 0.6*d for the masked ones.
// Candidates are written CONTIGUOUSLY per batch via one global atomicAdd per block
// (round-3 lesson: 16-block k_sel scanning 64K sparse slots was 149 us of latency).
__global__ void k_main(const float* __restrict__ yp, const float* __restrict__ yt,
                       const unsigned* __restrict__ hist1, unsigned* __restrict__ ccnt,
                       uint2* __restrict__ cand, double* __restrict__ accum) {
    __shared__ unsigned sh[NB1 + (NB1 >> 4)];
    __shared__ unsigned wave_sums[4];
    __shared__ unsigned s_sel, s_res;
    __shared__ unsigned cnt, s_base;
    __shared__ uint2 buf[1024];
    __shared__ float wsum[4];
    const int tid   = threadIdx.x;
    const int blk   = blockIdx.x;
    const int b     = blk >> 8;
    const int chunk = blk & 255;
    if (tid == 0) cnt = 0;

    const long base = (long)b * 3 * NPIX;
    const int  o    = (chunk * 256 + tid) * 4;

    // issue all heavy loads early; scan1 runs under their latency
    float4 p0 = *(const float4*)(yp + base + o);
    float4 p1 = *(const float4*)(yp + base + NPIX + o);
    float4 p2 = *(const float4*)(yp + base + 2 * NPIX + o);
    float4 t0 = *(const float4*)(yt + base + o);
    float4 t1 = *(const float4*)(yt + base + NPIX + o);
    float4 t2 = *(const float4*)(yt + base + 2 * NPIX + o);

    // ---- scan1 over hist1[b] ----
    const unsigned* hb = hist1 + b * NB1;
    for (int i = tid; i < NB1; i += 256) sh[PAD(i)] = hb[i];
    __syncthreads();
    scan4096(sh, wave_sums, tid, K_RANK, &s_sel, &s_res);
    __syncthreads();
    const unsigned sel = s_sel;

    // ---- loss body + candidate collect ----
    float s = 0.0f;
    {
        float g = (p0.x + p1.x + p2.x) / 3.0f;
        unsigned u = __float_as_uint(g);
        float d = fabsf(p0.x - t0.x) + fabsf(p1.x - t1.x) + fabsf(p2.x - t2.x);
        unsigned bin = u >> 20;
        s += ((bin < sel) ? 0.8f : 0.2f) * d;
        if (bin == sel) { unsigned i = atomicAdd(&cnt, 1u); buf[i] = make_uint2(u, __float_as_uint(d)); }
    }
    {
        float g = (p0.y + p1.y + p2.y) / 3.0f;
        unsigned u = __float_as_uint(g);
        float d = fabsf(p0.y - t0.y) + fabsf(p1.y - t1.y) + fabsf(p2.y - t2.y);
        unsigned bin = u >> 20;
        s += ((bin < sel) ? 0.8f : 0.2f) * d;
        if (bin == sel) { unsigned i = atomicAdd(&cnt, 1u); buf[i] = make_uint2(u, __float_as_uint(d)); }
    }
    {
        float g = (p0.z + p1.z + p2.z) / 3.0f;
        unsigned u = __float_as_uint(g);
        float d = fabsf(p0.z - t0.z) + fabsf(p1.z - t1.z) + fabsf(p2.z - t2.z);
        unsigned bin = u >> 20;
        s += ((bin < sel) ? 0.8f : 0.2f) * d;
        if (bin == sel) { unsigned i = atomicAdd(&cnt, 1u); buf[i] = make_uint2(u, __float_as_uint(d)); }
    }
    {
        float g = (p0.w + p1.w + p2.w) / 3.0f;
        unsigned u = __float_as_uint(g);
        float d = fabsf(p0.w - t0.w) + fabsf(p1.w - t1.w) + fabsf(p2.w - t2.w);
        unsigned bin = u >> 20;
        s += ((bin < sel) ? 0.8f : 0.2f) * d;
        if (bin == sel) { unsigned i = atomicAdd(&cnt, 1u); buf[i] = make_uint2(u, __float_as_uint(d)); }
    }
    __syncthreads();

    // reserve contiguous range for this block's candidates, write them packed
    if (tid == 0) s_base = cnt ? atomicAdd(&ccnt[b], cnt) : 0u;
    __syncthreads();
    const unsigned nn = cnt;
    const unsigned bs = s_base;
    for (unsigned i = (unsigned)tid; i < nn; i += 256) {
        unsigned slot = bs + i;
        if (slot < CAP) cand[(long)b * CAP + slot] = buf[i];
    }

    // block sum -> accum
    for (int off = 32; off > 0; off >>= 1) s += __shfl_down(s, off);
    if ((tid & 63) == 0) wsum[tid >> 6] = s;
    __syncthreads();
    if (tid == 0) {
        float tot = wsum[0] + wsum[1] + wsum[2] + wsum[3];
        atomicAdd(&accum[(blk & 63) * 16], (double)tot);   // 64 cache-line-spread slots
    }
}

// ---------------- K3: resolve low 20 threshold bits over COMPACTED candidates ----------------
// One block per batch; candidate list is dense (~5-20k entries), read 4/thread/iter.
__global__ void k_sel(const uint2* __restrict__ cand, const unsigned* __restrict__ hist1,
                      const unsigned* __restrict__ ccnt, double* __restrict__ accum) {
    __shared__ unsigned sh[NB1 + (NB1 >> 4)];
    __shared__ float    sd[NB1 + (NB1 >> 4)];
    __shared__ unsigned h3[256];
    __shared__ float    sd3[256];
    __shared__ unsigned wave_sums[4];
    __shared__ unsigned s_sel, s_r2, s_bin2, s_r3, s_low;
    __shared__ float red[4];
    const int tid = threadIdx.x;
    const int b   = blockIdx.x;

    if (tid == 0) { s_bin2 = 0; s_r3 = 0; s_low = 0; }
    const unsigned n = min(ccnt[b], (unsigned)CAP);

    // ---- scan1 of hist1[b] -> sel, r2 (residual rank within sel bin) ----
    const unsigned* hb = hist1 + b * NB1;
    for (int i = tid; i < NB1; i += 256) sh[PAD(i)] = hb[i];
    __syncthreads();
    scan4096(sh, wave_sums, tid, K_RANK, &s_sel, &s_r2);
    __syncthreads();
    const unsigned r2 = s_r2;

    // ---- zero hist2/sumd, h3/sd3 ----
    for (int i = tid; i < NB1; i += 256) { sh[PAD(i)] = 0u; sd[PAD(i)] = 0.0f; }
    h3[tid] = 0u; sd3[tid] = 0.0f;
    __syncthreads();

    const uint2* cb = cand + (long)b * CAP;

    // ---- pass 1: histogram candidates on bits[19:8] with per-bin d sums ----
    for (unsigned base0 = 0; base0 < n; base0 += 1024) {
        const unsigned idx = base0 + (unsigned)tid * 4u;
        if (idx + 4 <= n) {
            const uint4 a = *(const uint4*)(cb + idx);        // cands idx, idx+1
            const uint4 c = *(const uint4*)(cb + idx + 2);    // cands idx+2, idx+3
            unsigned bn;
            bn = (a.x >> 8) & 0xFFFu; atomicAdd(&sh[PAD(bn)], 1u); atomicAdd(&sd[PAD(bn)], __uint_as_float(a.y));
            bn = (a.z >> 8) & 0xFFFu; atomicAdd(&sh[PAD(bn)], 1u); atomicAdd(&sd[PAD(bn)], __uint_as_float(a.w));
            bn = (c.x >> 8) & 0xFFFu; atomicAdd(&sh[PAD(bn)], 1u); atomicAdd(&sd[PAD(bn)], __uint_as_float(c.y));
            bn = (c.z >> 8) & 0xFFFu; atomicAdd(&sh[PAD(bn)], 1u); atomicAdd(&sd[PAD(bn)], __uint_as_float(c.w));
        } else {
            for (unsigned k = idx; k < n && k < idx + 4u; ++k) {
                uint2 v = cb[k];
                unsigned bn = (v.x >> 8) & 0xFFFu;
                atomicAdd(&sh[PAD(bn)], 1u); atomicAdd(&sd[PAD(bn)], __uint_as_float(v.y));
            }
        }
    }
    __syncthreads();

    // ---- scan2 -> bin2 (bits 19:8), r3 ----
    scan4096(sh, wave_sums, tid, r2, &s_bin2, &s_r3);
    __syncthreads();
    const unsigned bin2 = s_bin2;
    const unsigned r3   = s_r3;

    // ---- S_pre = sum of d over candidate bins strictly below bin2 ----
    float lp = 0.0f;
    #pragma unroll
    for (int j = 0; j < 16; ++j) {
        unsigned gb = (unsigned)(tid * 16 + j);
        if (gb < bin2) lp += sd[tid * 17 + j];
    }
    for (int off = 32; off > 0; off >>= 1) lp += __shfl_down(lp, off);
    if ((tid & 63) == 0) red[tid >> 6] = lp;
    __syncthreads();
    const float S_pre = red[0] + red[1] + red[2] + red[3];
    __syncthreads();

    // ---- pass 2: final byte histogram within bin2 (list is L2-hot now) ----
    for (unsigned base0 = 0; base0 < n; base0 += 1024) {
        const unsigned idx = base0 + (unsigned)tid * 4u;
        if (idx + 4 <= n) {
            const uint4 a = *(const uint4*)(cb + idx);
            const uint4 c = *(const uint4*)(cb + idx + 2);
            if (((a.x >> 8) & 0xFFFu) == bin2) { atomicAdd(&h3[a.x & 0xFFu], 1u); atomicAdd(&sd3[a.x & 0xFFu], __uint_as_float(a.y)); }
            if (((a.z >> 8) & 0xFFFu) == bin2) { atomicAdd(&h3[a.z & 0xFFu], 1u); atomicAdd(&sd3[a.z & 0xFFu], __uint_as_float(a.w)); }
            if (((c.x >> 8) & 0xFFFu) == bin2) { atomicAdd(&h3[c.x & 0xFFu], 1u); atomicAdd(&sd3[c.x & 0xFFu], __uint_as_float(c.y)); }
            if (((c.z >> 8) & 0xFFFu) == bin2) { atomicAdd(&h3[c.z & 0xFFu], 1u); atomicAdd(&sd3[c.z & 0xFFu], __uint_as_float(c.w)); }
        } else {
            for (unsigned k = idx; k < n && k < idx + 4u; ++k) {
                uint2 v = cb[k];
                if (((v.x >> 8) & 0xFFFu) == bin2) { atomicAdd(&h3[v.x & 0xFFu], 1u); atomicAdd(&sd3[v.x & 0xFFu], __uint_as_float(v.y)); }
            }
        }
    }
    __syncthreads();

    // ---- scan3: 256 bins, one per thread -> low byte of threshold ----
    const unsigned sum = h3[tid];
    unsigned inc = sum;
    for (int off = 1; off < 64; off <<= 1) {
        unsigned v = __shfl_up(inc, off);
        if ((tid & 63) >= off) inc += v;
    }
    if ((tid & 63) == 63) wave_sums[tid >> 6] = inc;
    __syncthreads();
    unsigned woff = 0;
    for (int w = 0; w < (tid >> 6); ++w) woff += wave_sums[w];
    const unsigned excl = woff + inc - sum;
    if (sum > 0 && r3 >= excl && r3 < excl + sum) s_low = (unsigned)tid;
    __syncthreads();
    const unsigned low = s_low;

    // ---- S_b2 = sum of d over bin2 candidates with low byte <= low ----
    float l2 = ((unsigned)tid <= low) ? sd3[tid] : 0.0f;
    for (int off = 32; off > 0; off >>= 1) l2 += __shfl_down(l2, off);
    if ((tid & 63) == 0) red[tid >> 6] = l2;
    __syncthreads();
    if (tid == 0) {
        float S_b2 = red[0] + red[1] + red[2] + red[3];
        atomicAdd(&accum[(b & 63) * 16], 0.6 * ((double)S_pre + (double)S_b2));
    }
}

__global__ void k_final(const double* __restrict__ accum, float* __restrict__ out) {
    const int tid = threadIdx.x;      // 64 threads
    double v = accum[tid * 16];
    for (int off = 32; off > 0; off >>= 1) v += __shfl_down(v, off);
    if (tid == 0) out[0] = (float)(v / 12582912.0);   // 16*3*512*512
}

extern "C" void kernel_launch(void* const* d_in, const int* in_sizes, int n_in,
                              void* d_out, int out_size, void* d_ws, size_t ws_size,
                              hipStream_t stream) {
    const float* yt = (const float*)d_in[0];   // y_true
    const float* yp = (const float*)d_in[1];   // y_pred
    float* out = (float*)d_out;
    char* ws = (char*)d_ws;

    // ws layout
    unsigned* hist1 = (unsigned*)(ws);               // 262144 B (memset)
    double*   accum = (double*)(ws + 262144);        // 8192 B  (zeroed by k_hist zr path)
    unsigned* ccnt  = (unsigned*)(ws + 270336);      // 64 B    (zeroed by k_hist zr path)
    unsigned* zr    = (unsigned*)(ws + 262144);
    uint2*    cand  = (uint2*)(ws + (1 << 20));      // 16 * 262144 * 8 = 32 MB
    const int zcount = (8192 + 64) / 4;              // accum + ccnt

    hipMemsetAsync(hist1, 0, 262144, stream);        // hist1 only

    k_hist <<<4096, 256, 0, stream>>>(yp, hist1, zr, zcount);
    k_main <<<4096, 256, 0, stream>>>(yp, yt, hist1, ccnt, cand, accum);
    k_sel  <<<NB,   256, 0, stream>>>(cand, hist1, ccnt, accum);
    k_final<<<1,    64,  0, stream>>>(accum, out);
}

// Round 5
// 200.016 us; speedup vs baseline: 1.4144x; 1.0202x over previous
//
#include <hip/hip_runtime.h>
#include <stdint.h>

#define NB 16
#define NPIX 262144            // 512*512
#define K_RANK 104856u         // int(512*512*0.4 - 1)
#define NB1 4096
#define CAP 262144             // per-batch candidate capacity (compacted; worst case NPIX)
#define PAD(i) ((i) + ((i) >> 4))

// Shared scan over 4096 padded counts in sh[]; the single thread whose range
// contains rank r writes digit + residual rank to the out pointers.
__device__ inline void scan4096(const unsigned* __restrict__ sh, unsigned* wave_sums,
                                int tid, unsigned r,
                                unsigned* out_digit, unsigned* out_res) {
    unsigned sum = 0;
    #pragma unroll
    for (int j = 0; j < 16; ++j) sum += sh[tid * 17 + j];
    unsigned inc = sum;
    for (int off = 1; off < 64; off <<= 1) {
        unsigned v = __shfl_up(inc, off);
        if ((tid & 63) >= off) inc += v;
    }
    if ((tid & 63) == 63) wave_sums[tid >> 6] = inc;
    __syncthreads();
    unsigned woff = 0;
    for (int w = 0; w < (tid >> 6); ++w) woff += wave_sums[w];
    const unsigned excl = woff + inc - sum;
    if (r >= excl && r < excl + sum) {            // exactly one thread
        unsigned cum = excl;
        unsigned d   = (unsigned)(tid * 16);
        #pragma unroll
        for (int j = 0; j < 16; ++j) {
            unsigned c = sh[tid * 17 + j];
            if (cum + c > r) { d = (unsigned)(tid * 16 + j); break; }
            cum += c;
        }
        *out_digit = d;
        *out_res   = r - cum;
    }
}

// ---------------- K1: gray + histogram on float bits[31:20] + zero accum/ccnt ----------------
__global__ void k_hist(const float* __restrict__ yp, unsigned* __restrict__ hist1,
                       unsigned* __restrict__ zr, int zcount) {
    __shared__ unsigned h[NB1];
    const int tid = threadIdx.x;
    const int gtid = blockIdx.x * 256 + tid;
    if (gtid < zcount) zr[gtid] = 0;   // zero accum + ccnt (consumed only by later kernels)
    for (int i = tid; i < NB1; i += 256) h[i] = 0;
    __syncthreads();

    const int blk   = blockIdx.x;      // 4096 blocks, 256 per batch
    const int b     = blk >> 8;
    const int chunk = blk & 255;
    const long base = (long)b * 3 * NPIX;
    const int  o    = (chunk * 256 + tid) * 4;

    const float4 c0 = *(const float4*)(yp + base + o);
    const float4 c1 = *(const float4*)(yp + base + NPIX + o);
    const float4 c2 = *(const float4*)(yp + base + 2 * NPIX + o);

    atomicAdd(&h[__float_as_uint((c0.x + c1.x + c2.x) / 3.0f) >> 20], 1u);
    atomicAdd(&h[__float_as_uint((c0.y + c1.y + c2.y) / 3.0f) >> 20], 1u);
    atomicAdd(&h[__float_as_uint((c0.z + c1.z + c2.z) / 3.0f) >> 20], 1u);
    atomicAdd(&h[__float_as_uint((c0.w + c1.w + c2.w) / 3.0f) >> 20], 1u);
    __syncthreads();

    unsigned* gh = hist1 + b * NB1;
    for (int i = tid; i < NB1; i += 256) {
        unsigned v = h[i];
        if (v) atomicAdd(&gh[i], v);   // non-returning; only ~50 bins nonzero
    }
}

// ---------------- K2: tiny scan1 — one block per batch -> sel bin + residual rank ----------------
// Round-4 lesson: fusing this into the heavy pixel pass forced VGPR=24, sank the
// pixel loads below the scan, and cost 65 us. As a 16-block kernel it's ~3-4 us.
__global__ void k_scan(const unsigned* __restrict__ hist1,
                       unsigned* __restrict__ selbin, unsigned* __restrict__ resrank) {
    __shared__ unsigned sh[NB1 + (NB1 >> 4)];
    __shared__ unsigned wave_sums[4];
    const int b   = blockIdx.x;
    const int tid = threadIdx.x;
    const unsigned* hb = hist1 + b * NB1;
    for (int i = tid; i < NB1; i += 256) sh[PAD(i)] = hb[i];
    __syncthreads();
    scan4096(sh, wave_sums, tid, K_RANK, &selbin[b], &resrank[b]);
}

// ---------------- K3: loss + compacted candidate collection (no scan, lean LDS) ----------------
// Weight fully determined outside the selected bin (0.8 below / 0.2 above); sel-bin
// pixels get 0.2 here and k_sel adds the remaining 0.6*d for the masked subset.
__global__ void k_main(const float* __restrict__ yp, const float* __restrict__ yt,
                       const unsigned* __restrict__ selbin, unsigned* __restrict__ ccnt,
                       uint2* __restrict__ cand, double* __restrict__ accum) {
    __shared__ uint2 buf[1024];
    __shared__ unsigned cnt, s_base;
    __shared__ float wsum[4];
    const int tid   = threadIdx.x;
    const int blk   = blockIdx.x;
    const int b     = blk >> 8;
    const int chunk = blk & 255;
    if (tid == 0) cnt = 0;

    const long base = (long)b * 3 * NPIX;
    const int  o    = (chunk * 256 + tid) * 4;

    const float4 p0 = *(const float4*)(yp + base + o);
    const float4 p1 = *(const float4*)(yp + base + NPIX + o);
    const float4 p2 = *(const float4*)(yp + base + 2 * NPIX + o);
    const float4 t0 = *(const float4*)(yt + base + o);
    const float4 t1 = *(const float4*)(yt + base + NPIX + o);
    const float4 t2 = *(const float4*)(yt + base + 2 * NPIX + o);
    const unsigned sel = selbin[b];
    __syncthreads();   // cnt=0 visible (loads drain here anyway; they're needed next)

    float s = 0.0f;
    {
        float g = (p0.x + p1.x + p2.x) / 3.0f;
        unsigned u = __float_as_uint(g);
        float d = fabsf(p0.x - t0.x) + fabsf(p1.x - t1.x) + fabsf(p2.x - t2.x);
        unsigned bin = u >> 20;
        s += ((bin < sel) ? 0.8f : 0.2f) * d;
        if (bin == sel) { unsigned i = atomicAdd(&cnt, 1u); buf[i] = make_uint2(u, __float_as_uint(d)); }
    }
    {
        float g = (p0.y + p1.y + p2.y) / 3.0f;
        unsigned u = __float_as_uint(g);
        float d = fabsf(p0.y - t0.y) + fabsf(p1.y - t1.y) + fabsf(p2.y - t2.y);
        unsigned bin = u >> 20;
        s += ((bin < sel) ? 0.8f : 0.2f) * d;
        if (bin == sel) { unsigned i = atomicAdd(&cnt, 1u); buf[i] = make_uint2(u, __float_as_uint(d)); }
    }
    {
        float g = (p0.z + p1.z + p2.z) / 3.0f;
        unsigned u = __float_as_uint(g);
        float d = fabsf(p0.z - t0.z) + fabsf(p1.z - t1.z) + fabsf(p2.z - t2.z);
        unsigned bin = u >> 20;
        s += ((bin < sel) ? 0.8f : 0.2f) * d;
        if (bin == sel) { unsigned i = atomicAdd(&cnt, 1u); buf[i] = make_uint2(u, __float_as_uint(d)); }
    }
    {
        float g = (p0.w + p1.w + p2.w) / 3.0f;
        unsigned u = __float_as_uint(g);
        float d = fabsf(p0.w - t0.w) + fabsf(p1.w - t1.w) + fabsf(p2.w - t2.w);
        unsigned bin = u >> 20;
        s += ((bin < sel) ? 0.8f : 0.2f) * d;
        if (bin == sel) { unsigned i = atomicAdd(&cnt, 1u); buf[i] = make_uint2(u, __float_as_uint(d)); }
    }
    __syncthreads();

    // reserve contiguous range for this block's candidates, write them packed
    if (tid == 0) s_base = cnt ? atomicAdd(&ccnt[b], cnt) : 0u;
    __syncthreads();
    const unsigned nn = cnt;
    const unsigned bs = s_base;
    for (unsigned i = (unsigned)tid; i < nn; i += 256) {
        unsigned slot = bs + i;
        if (slot < CAP) cand[(long)b * CAP + slot] = buf[i];
    }

    // block sum -> accum
    for (int off = 32; off > 0; off >>= 1) s += __shfl_down(s, off);
    if ((tid & 63) == 0) wsum[tid >> 6] = s;
    __syncthreads();
    if (tid == 0) {
        float tot = wsum[0] + wsum[1] + wsum[2] + wsum[3];
        atomicAdd(&accum[(blk & 63) * 16], (double)tot);   // 64 cache-line-spread slots
    }
}

// ---------------- K4: resolve low 20 threshold bits over compacted candidates ----------------
// One block per batch; candidate list is dense (~5-20k entries), read 4/thread/iter.
__global__ void k_sel(const uint2* __restrict__ cand, const unsigned* __restrict__ resrank,
                      const unsigned* __restrict__ ccnt, double* __restrict__ accum) {
    __shared__ unsigned sh[NB1 + (NB1 >> 4)];
    __shared__ float    sd[NB1 + (NB1 >> 4)];
    __shared__ unsigned h3[256];
    __shared__ float    sd3[256];
    __shared__ unsigned wave_sums[4];
    __shared__ unsigned s_bin2, s_r3, s_low;
    __shared__ float red[4];
    const int tid = threadIdx.x;
    const int b   = blockIdx.x;

    if (tid == 0) { s_bin2 = 0; s_r3 = 0; s_low = 0; }
    const unsigned n  = min(ccnt[b], (unsigned)CAP);
    const unsigned r2 = resrank[b];

    for (int i = tid; i < NB1; i += 256) { sh[PAD(i)] = 0u; sd[PAD(i)] = 0.0f; }
    h3[tid] = 0u; sd3[tid] = 0.0f;
    __syncthreads();

    const uint2* cb = cand + (long)b * CAP;

    // ---- pass 1: histogram candidates on bits[19:8] with per-bin d sums ----
    for (unsigned base0 = 0; base0 < n; base0 += 1024) {
        const unsigned idx = base0 + (unsigned)tid * 4u;
        if (idx + 4 <= n) {
            const uint4 a = *(const uint4*)(cb + idx);        // cands idx, idx+1
            const uint4 c = *(const uint4*)(cb + idx + 2);    // cands idx+2, idx+3
            unsigned bn;
            bn = (a.x >> 8) & 0xFFFu; atomicAdd(&sh[PAD(bn)], 1u); atomicAdd(&sd[PAD(bn)], __uint_as_float(a.y));
            bn = (a.z >> 8) & 0xFFFu; atomicAdd(&sh[PAD(bn)], 1u); atomicAdd(&sd[PAD(bn)], __uint_as_float(a.w));
            bn = (c.x >> 8) & 0xFFFu; atomicAdd(&sh[PAD(bn)], 1u); atomicAdd(&sd[PAD(bn)], __uint_as_float(c.y));
            bn = (c.z >> 8) & 0xFFFu; atomicAdd(&sh[PAD(bn)], 1u); atomicAdd(&sd[PAD(bn)], __uint_as_float(c.w));
        } else {
            for (unsigned k = idx; k < n && k < idx + 4u; ++k) {
                uint2 v = cb[k];
                unsigned bn = (v.x >> 8) & 0xFFFu;
                atomicAdd(&sh[PAD(bn)], 1u); atomicAdd(&sd[PAD(bn)], __uint_as_float(v.y));
            }
        }
    }
    __syncthreads();

    // ---- scan2 -> bin2 (bits 19:8), r3 ----
    scan4096(sh, wave_sums, tid, r2, &s_bin2, &s_r3);
    __syncthreads();
    const unsigned bin2 = s_bin2;
    const unsigned r3   = s_r3;

    // ---- S_pre = sum of d over candidate bins strictly below bin2 ----
    float lp = 0.0f;
    #pragma unroll
    for (int j = 0; j < 16; ++j) {
        unsigned gb = (unsigned)(tid * 16 + j);
        if (gb < bin2) lp += sd[tid * 17 + j];
    }
    for (int off = 32; off > 0; off >>= 1) lp += __shfl_down(lp, off);
    if ((tid & 63) == 0) red[tid >> 6] = lp;
    __syncthreads();
    const float S_pre = red[0] + red[1] + red[2] + red[3];
    __syncthreads();

    // ---- pass 2: final byte histogram within bin2 (list is L2-hot now) ----
    for (unsigned base0 = 0; base0 < n; base0 += 1024) {
        const unsigned idx = base0 + (unsigned)tid * 4u;
        if (idx + 4 <= n) {
            const uint4 a = *(const uint4*)(cb + idx);
            const uint4 c = *(const uint4*)(cb + idx + 2);
            if (((a.x >> 8) & 0xFFFu) == bin2) { atomicAdd(&h3[a.x & 0xFFu], 1u); atomicAdd(&sd3[a.x & 0xFFu], __uint_as_float(a.y)); }
            if (((a.z >> 8) & 0xFFFu) == bin2) { atomicAdd(&h3[a.z & 0xFFu], 1u); atomicAdd(&sd3[a.z & 0xFFu], __uint_as_float(a.w)); }
            if (((c.x >> 8) & 0xFFFu) == bin2) { atomicAdd(&h3[c.x & 0xFFu], 1u); atomicAdd(&sd3[c.x & 0xFFu], __uint_as_float(c.y)); }
            if (((c.z >> 8) & 0xFFFu) == bin2) { atomicAdd(&h3[c.z & 0xFFu], 1u); atomicAdd(&sd3[c.z & 0xFFu], __uint_as_float(c.w)); }
        } else {
            for (unsigned k = idx; k < n && k < idx + 4u; ++k) {
                uint2 v = cb[k];
                if (((v.x >> 8) & 0xFFFu) == bin2) { atomicAdd(&h3[v.x & 0xFFu], 1u); atomicAdd(&sd3[v.x & 0xFFu], __uint_as_float(v.y)); }
            }
        }
    }
    __syncthreads();

    // ---- scan3: 256 bins, one per thread -> low byte of threshold ----
    const unsigned sum = h3[tid];
    unsigned inc = sum;
    for (int off = 1; off < 64; off <<= 1) {
        unsigned v = __shfl_up(inc, off);
        if ((tid & 63) >= off) inc += v;
    }
    if ((tid & 63) == 63) wave_sums[tid >> 6] = inc;
    __syncthreads();
    unsigned woff = 0;
    for (int w = 0; w < (tid >> 6); ++w) woff += wave_sums[w];
    const unsigned excl = woff + inc - sum;
    if (sum > 0 && r3 >= excl && r3 < excl + sum) s_low = (unsigned)tid;
    __syncthreads();
    const unsigned low = s_low;

    // ---- S_b2 = sum of d over bin2 candidates with low byte <= low ----
    float l2 = ((unsigned)tid <= low) ? sd3[tid] : 0.0f;
    for (int off = 32; off > 0; off >>= 1) l2 += __shfl_down(l2, off);
    if ((tid & 63) == 0) red[tid >> 6] = l2;
    __syncthreads();
    if (tid == 0) {
        float S_b2 = red[0] + red[1] + red[2] + red[3];
        atomicAdd(&accum[(b & 63) * 16], 0.6 * ((double)S_pre + (double)S_b2));
    }
}

__global__ void k_final(const double* __restrict__ accum, float* __restrict__ out) {
    const int tid = threadIdx.x;      // 64 threads
    double v = accum[tid * 16];
    for (int off = 32; off > 0; off >>= 1) v += __shfl_down(v, off);
    if (tid == 0) out[0] = (float)(v / 12582912.0);   // 16*3*512*512
}

extern "C" void kernel_launch(void* const* d_in, const int* in_sizes, int n_in,
                              void* d_out, int out_size, void* d_ws, size_t ws_size,
                              hipStream_t stream) {
    const float* yt = (const float*)d_in[0];   // y_true
    const float* yp = (const float*)d_in[1];   // y_pred
    float* out = (float*)d_out;
    char* ws = (char*)d_ws;

    // ws layout
    unsigned* hist1  = (unsigned*)(ws);               // 262144 B (memset)
    double*   accum  = (double*)(ws + 262144);        // 8192 B  (zeroed by k_hist zr path)
    unsigned* ccnt   = (unsigned*)(ws + 270336);      // 64 B    (zeroed by k_hist zr path)
    unsigned* zr     = (unsigned*)(ws + 262144);
    unsigned* selbin = (unsigned*)(ws + 270400);      // 64 B (written by k_scan before reads)
    unsigned* resrnk = (unsigned*)(ws + 270464);      // 64 B
    uint2*    cand   = (uint2*)(ws + (1 << 20));      // 16 * 262144 * 8 = 32 MB
    const int zcount = (8192 + 64) / 4;               // accum + ccnt

    hipMemsetAsync(hist1, 0, 262144, stream);         // hist1 only

    k_hist <<<4096, 256, 0, stream>>>(yp, hist1, zr, zcount);
    k_scan <<<NB,   256, 0, stream>>>(hist1, selbin, resrnk);
    k_main <<<4096, 256, 0, stream>>>(yp, yt, selbin, ccnt, cand, accum);
    k_sel  <<<NB,   256, 0, stream>>>(cand, resrnk, ccnt, accum);
    k_final<<<1,    64,  0, stream>>>(accum, out);
}

// Round 6
// 181.233 us; speedup vs baseline: 1.5610x; 1.1036x over previous
//
#include <hip/hip_runtime.h>
#include <stdint.h>

#define NB 16
#define NPIX 262144            // 512*512
#define K_RANK 104856u         // int(512*512*0.4 - 1)
#define NB1 4096
#define NSEG 16                // sub-lists per batch (breaks the ccnt atomic chain 16x)
#define SEGCAP 16384           // 16 chunks * 1024 pixels: cannot overflow
#define PAD(i) ((i) + ((i) >> 4))

// Shared scan over 4096 padded counts in sh[]; the single thread whose range
// contains rank r writes digit + residual rank to the out pointers.
__device__ inline void scan4096(const unsigned* __restrict__ sh, unsigned* wave_sums,
                                int tid, unsigned r,
                                unsigned* out_digit, unsigned* out_res) {
    unsigned sum = 0;
    #pragma unroll
    for (int j = 0; j < 16; ++j) sum += sh[tid * 17 + j];
    unsigned inc = sum;
    for (int off = 1; off < 64; off <<= 1) {
        unsigned v = __shfl_up(inc, off);
        if ((tid & 63) >= off) inc += v;
    }
    if ((tid & 63) == 63) wave_sums[tid >> 6] = inc;
    __syncthreads();
    unsigned woff = 0;
    for (int w = 0; w < (tid >> 6); ++w) woff += wave_sums[w];
    const unsigned excl = woff + inc - sum;
    if (r >= excl && r < excl + sum) {            // exactly one thread
        unsigned cum = excl;
        unsigned d   = (unsigned)(tid * 16);
        #pragma unroll
        for (int j = 0; j < 16; ++j) {
            unsigned c = sh[tid * 17 + j];
            if (cum + c > r) { d = (unsigned)(tid * 16 + j); break; }
            cum += c;
        }
        *out_digit = d;
        *out_res   = r - cum;
    }
}

// ---------------- K1: gray + histogram on float bits[31:20] + zero accum/ccnt ----------------
__global__ void k_hist(const float* __restrict__ yp, unsigned* __restrict__ hist1,
                       unsigned* __restrict__ zr, int zcount) {
    __shared__ unsigned h[NB1];
    const int tid = threadIdx.x;
    const int gtid = blockIdx.x * 256 + tid;
    if (gtid < zcount) zr[gtid] = 0;   // zero accum + ccnt (consumed only by later kernels)
    for (int i = tid; i < NB1; i += 256) h[i] = 0;
    __syncthreads();

    const int blk   = blockIdx.x;      // 4096 blocks, 256 per batch
    const int b     = blk >> 8;
    const int chunk = blk & 255;
    const long base = (long)b * 3 * NPIX;
    const int  o    = (chunk * 256 + tid) * 4;

    const float4 c0 = *(const float4*)(yp + base + o);
    const float4 c1 = *(const float4*)(yp + base + NPIX + o);
    const float4 c2 = *(const float4*)(yp + base + 2 * NPIX + o);

    atomicAdd(&h[__float_as_uint((c0.x + c1.x + c2.x) / 3.0f) >> 20], 1u);
    atomicAdd(&h[__float_as_uint((c0.y + c1.y + c2.y) / 3.0f) >> 20], 1u);
    atomicAdd(&h[__float_as_uint((c0.z + c1.z + c2.z) / 3.0f) >> 20], 1u);
    atomicAdd(&h[__float_as_uint((c0.w + c1.w + c2.w) / 3.0f) >> 20], 1u);
    __syncthreads();

    unsigned* gh = hist1 + b * NB1;
    for (int i = tid; i < NB1; i += 256) {
        unsigned v = h[i];
        if (v) atomicAdd(&gh[i], v);   // non-returning; only ~50 bins nonzero
    }
}

// ---------------- K2: tiny scan1 — one block per batch -> sel bin + residual rank ----------------
__global__ void k_scan(const unsigned* __restrict__ hist1,
                       unsigned* __restrict__ selbin, unsigned* __restrict__ resrank) {
    __shared__ unsigned sh[NB1 + (NB1 >> 4)];
    __shared__ unsigned wave_sums[4];
    const int b   = blockIdx.x;
    const int tid = threadIdx.x;
    const unsigned* hb = hist1 + b * NB1;
    for (int i = tid; i < NB1; i += 256) sh[PAD(i)] = hb[i];
    __syncthreads();
    scan4096(sh, wave_sums, tid, K_RANK, &selbin[b], &resrank[b]);
}

// ---------------- K3: loss + segmented compacted candidate collection ----------------
// Round-5 lesson: ONE returning atomicAdd per block to 16 contended addresses made a
// 256-deep serialized RMW chain (~235 ns each = 60 us) with all waves parked at the
// barrier behind it. Fix: 16 sub-lists per batch (seg = chunk>>4) -> chains of 16.
__global__ void k_main(const float* __restrict__ yp, const float* __restrict__ yt,
                       const unsigned* __restrict__ selbin, unsigned* __restrict__ ccnt,
                       uint2* __restrict__ cand, double* __restrict__ accum) {
    __shared__ uint2 buf[1024];
    __shared__ unsigned cnt, s_base;
    __shared__ float wsum[4];
    const int tid   = threadIdx.x;
    const int blk   = blockIdx.x;
    const int b     = blk >> 8;
    const int chunk = blk & 255;
    const int seg   = chunk >> 4;
    if (tid == 0) cnt = 0;

    const long base = (long)b * 3 * NPIX;
    const int  o    = (chunk * 256 + tid) * 4;

    const float4 p0 = *(const float4*)(yp + base + o);
    const float4 p1 = *(const float4*)(yp + base + NPIX + o);
    const float4 p2 = *(const float4*)(yp + base + 2 * NPIX + o);
    const float4 t0 = *(const float4*)(yt + base + o);
    const float4 t1 = *(const float4*)(yt + base + NPIX + o);
    const float4 t2 = *(const float4*)(yt + base + 2 * NPIX + o);
    const unsigned sel = selbin[b];
    __syncthreads();   // cnt=0 visible

    float s = 0.0f;
    {
        float g = (p0.x + p1.x + p2.x) / 3.0f;
        unsigned u = __float_as_uint(g);
        float d = fabsf(p0.x - t0.x) + fabsf(p1.x - t1.x) + fabsf(p2.x - t2.x);
        unsigned bin = u >> 20;
        s += ((bin < sel) ? 0.8f : 0.2f) * d;
        if (bin == sel) { unsigned i = atomicAdd(&cnt, 1u); buf[i] = make_uint2(u, __float_as_uint(d)); }
    }
    {
        float g = (p0.y + p1.y + p2.y) / 3.0f;
        unsigned u = __float_as_uint(g);
        float d = fabsf(p0.y - t0.y) + fabsf(p1.y - t1.y) + fabsf(p2.y - t2.y);
        unsigned bin = u >> 20;
        s += ((bin < sel) ? 0.8f : 0.2f) * d;
        if (bin == sel) { unsigned i = atomicAdd(&cnt, 1u); buf[i] = make_uint2(u, __float_as_uint(d)); }
    }
    {
        float g = (p0.z + p1.z + p2.z) / 3.0f;
        unsigned u = __float_as_uint(g);
        float d = fabsf(p0.z - t0.z) + fabsf(p1.z - t1.z) + fabsf(p2.z - t2.z);
        unsigned bin = u >> 20;
        s += ((bin < sel) ? 0.8f : 0.2f) * d;
        if (bin == sel) { unsigned i = atomicAdd(&cnt, 1u); buf[i] = make_uint2(u, __float_as_uint(d)); }
    }
    {
        float g = (p0.w + p1.w + p2.w) / 3.0f;
        unsigned u = __float_as_uint(g);
        float d = fabsf(p0.w - t0.w) + fabsf(p1.w - t1.w) + fabsf(p2.w - t2.w);
        unsigned bin = u >> 20;
        s += ((bin < sel) ? 0.8f : 0.2f) * d;
        if (bin == sel) { unsigned i = atomicAdd(&cnt, 1u); buf[i] = make_uint2(u, __float_as_uint(d)); }
    }
    __syncthreads();

    // reserve contiguous range in this chunk-group's sub-list (16 contenders max)
    if (tid == 0) s_base = cnt ? atomicAdd(&ccnt[b * NSEG + seg], cnt) : 0u;
    __syncthreads();
    const unsigned nn = cnt;
    const unsigned bs = s_base;
    uint2* dst = cand + ((long)b * NSEG + seg) * SEGCAP;
    for (unsigned i = (unsigned)tid; i < nn; i += 256) {
        unsigned slot = bs + i;
        if (slot < SEGCAP) dst[slot] = buf[i];
    }

    // block sum -> accum
    for (int off = 32; off > 0; off >>= 1) s += __shfl_down(s, off);
    if ((tid & 63) == 0) wsum[tid >> 6] = s;
    __syncthreads();
    if (tid == 0) {
        float tot = wsum[0] + wsum[1] + wsum[2] + wsum[3];
        atomicAdd(&accum[(blk & 63) * 16], (double)tot);   // 64 cache-line-spread slots
    }
}

// ---------------- K4: resolve low 20 threshold bits over segmented candidates ----------------
// One block per batch; 16 dense segments (~1k entries each), read 4/thread/iter.
__global__ void k_sel(const uint2* __restrict__ cand, const unsigned* __restrict__ resrank,
                      const unsigned* __restrict__ ccnt, double* __restrict__ accum) {
    __shared__ unsigned sh[NB1 + (NB1 >> 4)];
    __shared__ float    sd[NB1 + (NB1 >> 4)];
    __shared__ unsigned h3[256];
    __shared__ float    sd3[256];
    __shared__ unsigned wave_sums[4];
    __shared__ unsigned s_bin2, s_r3, s_low;
    __shared__ float red[4];
    const int tid = threadIdx.x;
    const int b   = blockIdx.x;

    if (tid == 0) { s_bin2 = 0; s_r3 = 0; s_low = 0; }
    const unsigned r2 = resrank[b];

    for (int i = tid; i < NB1; i += 256) { sh[PAD(i)] = 0u; sd[PAD(i)] = 0.0f; }
    h3[tid] = 0u; sd3[tid] = 0.0f;
    __syncthreads();

    // ---- pass 1: histogram candidates on bits[19:8] with per-bin d sums ----
    for (int seg = 0; seg < NSEG; ++seg) {
        const unsigned n = min(ccnt[b * NSEG + seg], (unsigned)SEGCAP);
        const uint2* cb = cand + ((long)b * NSEG + seg) * SEGCAP;
        for (unsigned base0 = 0; base0 < n; base0 += 1024) {
            const unsigned idx = base0 + (unsigned)tid * 4u;
            if (idx + 4 <= n) {
                const uint4 a = *(const uint4*)(cb + idx);        // cands idx, idx+1
                const uint4 c = *(const uint4*)(cb + idx + 2);    // cands idx+2, idx+3
                unsigned bn;
                bn = (a.x >> 8) & 0xFFFu; atomicAdd(&sh[PAD(bn)], 1u); atomicAdd(&sd[PAD(bn)], __uint_as_float(a.y));
                bn = (a.z >> 8) & 0xFFFu; atomicAdd(&sh[PAD(bn)], 1u); atomicAdd(&sd[PAD(bn)], __uint_as_float(a.w));
                bn = (c.x >> 8) & 0xFFFu; atomicAdd(&sh[PAD(bn)], 1u); atomicAdd(&sd[PAD(bn)], __uint_as_float(c.y));
                bn = (c.z >> 8) & 0xFFFu; atomicAdd(&sh[PAD(bn)], 1u); atomicAdd(&sd[PAD(bn)], __uint_as_float(c.w));
            } else {
                for (unsigned k = idx; k < n && k < idx + 4u; ++k) {
                    uint2 v = cb[k];
                    unsigned bn = (v.x >> 8) & 0xFFFu;
                    atomicAdd(&sh[PAD(bn)], 1u); atomicAdd(&sd[PAD(bn)], __uint_as_float(v.y));
                }
            }
        }
    }
    __syncthreads();

    // ---- scan2 -> bin2 (bits 19:8), r3 ----
    scan4096(sh, wave_sums, tid, r2, &s_bin2, &s_r3);
    __syncthreads();
    const unsigned bin2 = s_bin2;
    const unsigned r3   = s_r3;

    // ---- S_pre = sum of d over candidate bins strictly below bin2 ----
    float lp = 0.0f;
    #pragma unroll
    for (int j = 0; j < 16; ++j) {
        unsigned gb = (unsigned)(tid * 16 + j);
        if (gb < bin2) lp += sd[tid * 17 + j];
    }
    for (int off = 32; off > 0; off >>= 1) lp += __shfl_down(lp, off);
    if ((tid & 63) == 0) red[tid >> 6] = lp;
    __syncthreads();
    const float S_pre = red[0] + red[1] + red[2] + red[3];
    __syncthreads();

    // ---- pass 2: final byte histogram within bin2 (segments are L2-hot) ----
    for (int seg = 0; seg < NSEG; ++seg) {
        const unsigned n = min(ccnt[b * NSEG + seg], (unsigned)SEGCAP);
        const uint2* cb = cand + ((long)b * NSEG + seg) * SEGCAP;
        for (unsigned base0 = 0; base0 < n; base0 += 1024) {
            const unsigned idx = base0 + (unsigned)tid * 4u;
            if (idx + 4 <= n) {
                const uint4 a = *(const uint4*)(cb + idx);
                const uint4 c = *(const uint4*)(cb + idx + 2);
                if (((a.x >> 8) & 0xFFFu) == bin2) { atomicAdd(&h3[a.x & 0xFFu], 1u); atomicAdd(&sd3[a.x & 0xFFu], __uint_as_float(a.y)); }
                if (((a.z >> 8) & 0xFFFu) == bin2) { atomicAdd(&h3[a.z & 0xFFu], 1u); atomicAdd(&sd3[a.z & 0xFFu], __uint_as_float(a.w)); }
                if (((c.x >> 8) & 0xFFFu) == bin2) { atomicAdd(&h3[c.x & 0xFFu], 1u); atomicAdd(&sd3[c.x & 0xFFu], __uint_as_float(c.y)); }
                if (((c.z >> 8) & 0xFFFu) == bin2) { atomicAdd(&h3[c.z & 0xFFu], 1u); atomicAdd(&sd3[c.z & 0xFFu], __uint_as_float(c.w)); }
            } else {
                for (unsigned k = idx; k < n && k < idx + 4u; ++k) {
                    uint2 v = cb[k];
                    if (((v.x >> 8) & 0xFFFu) == bin2) { atomicAdd(&h3[v.x & 0xFFu], 1u); atomicAdd(&sd3[v.x & 0xFFu], __uint_as_float(v.y)); }
                }
            }
        }
    }
    __syncthreads();

    // ---- scan3: 256 bins, one per thread -> low byte of threshold ----
    const unsigned sum = h3[tid];
    unsigned inc = sum;
    for (int off = 1; off < 64; off <<= 1) {
        unsigned v = __shfl_up(inc, off);
        if ((tid & 63) >= off) inc += v;
    }
    if ((tid & 63) == 63) wave_sums[tid >> 6] = inc;
    __syncthreads();
    unsigned woff = 0;
    for (int w = 0; w < (tid >> 6); ++w) woff += wave_sums[w];
    const unsigned excl = woff + inc - sum;
    if (sum > 0 && r3 >= excl && r3 < excl + sum) s_low = (unsigned)tid;
    __syncthreads();
    const unsigned low = s_low;

    // ---- S_b2 = sum of d over bin2 candidates with low byte <= low ----
    float l2 = ((unsigned)tid <= low) ? sd3[tid] : 0.0f;
    for (int off = 32; off > 0; off >>= 1) l2 += __shfl_down(l2, off);
    if ((tid & 63) == 0) red[tid >> 6] = l2;
    __syncthreads();
    if (tid == 0) {
        float S_b2 = red[0] + red[1] + red[2] + red[3];
        atomicAdd(&accum[(b & 63) * 16], 0.6 * ((double)S_pre + (double)S_b2));
    }
}

__global__ void k_final(const double* __restrict__ accum, float* __restrict__ out) {
    const int tid = threadIdx.x;      // 64 threads
    double v = accum[tid * 16];
    for (int off = 32; off > 0; off >>= 1) v += __shfl_down(v, off);
    if (tid == 0) out[0] = (float)(v / 12582912.0);   // 16*3*512*512
}

extern "C" void kernel_launch(void* const* d_in, const int* in_sizes, int n_in,
                              void* d_out, int out_size, void* d_ws, size_t ws_size,
                              hipStream_t stream) {
    const float* yt = (const float*)d_in[0];   // y_true
    const float* yp = (const float*)d_in[1];   // y_pred
    float* out = (float*)d_out;
    char* ws = (char*)d_ws;

    // ws layout
    unsigned* hist1  = (unsigned*)(ws);               // 262144 B (memset)
    double*   accum  = (double*)(ws + 262144);        // 8192 B  (zeroed by k_hist zr path)
    unsigned* ccnt   = (unsigned*)(ws + 270336);      // 16*16*4 = 1024 B (zeroed by zr path)
    unsigned* zr     = (unsigned*)(ws + 262144);
    unsigned* selbin = (unsigned*)(ws + 271360);      // 64 B (written by k_scan before reads)
    unsigned* resrnk = (unsigned*)(ws + 271424);      // 64 B
    uint2*    cand   = (uint2*)(ws + (1 << 20));      // 16 * 16 * 16384 * 8 = 32 MB
    const int zcount = (8192 + 1024) / 4;             // accum + ccnt

    hipMemsetAsync(hist1, 0, 262144, stream);         // hist1 only

    k_hist <<<4096, 256, 0, stream>>>(yp, hist1, zr, zcount);
    k_scan <<<NB,   256, 0, stream>>>(hist1, selbin, resrnk);
    k_main <<<4096, 256, 0, stream>>>(yp, yt, selbin, ccnt, cand, accum);
    k_sel  <<<NB,   256, 0, stream>>>(cand, resrnk, ccnt, accum);
    k_final<<<1,    64,  0, stream>>>(accum, out);
}

// Round 7
// 168.050 us; speedup vs baseline: 1.6835x; 1.0784x over previous
//
#include <hip/hip_runtime.h>
#include <stdint.h>

#define NB 16
#define NPIX 262144            // 512*512
#define K_RANK 104856u         // int(512*512*0.4 - 1)
#define NB1 4096
#define NSEG 16                // sub-lists per batch (breaks the ccnt atomic chain 16x)
#define SEGCAP 16384           // 16 chunks * 1024 pixels: cannot overflow
#define STAGE_CAP 12288        // LDS staging capacity in k_sel (96 KB); overflow -> global path
#define PAD(i) ((i) + ((i) >> 4))

// Shared scan over 4096 padded counts in sh[]; the single thread whose range
// contains rank r writes digit + residual rank to the out pointers.
__device__ inline void scan4096(const unsigned* __restrict__ sh, unsigned* wave_sums,
                                int tid, unsigned r,
                                unsigned* out_digit, unsigned* out_res) {
    unsigned sum = 0;
    #pragma unroll
    for (int j = 0; j < 16; ++j) sum += sh[tid * 17 + j];
    unsigned inc = sum;
    for (int off = 1; off < 64; off <<= 1) {
        unsigned v = __shfl_up(inc, off);
        if ((tid & 63) >= off) inc += v;
    }
    if ((tid & 63) == 63) wave_sums[tid >> 6] = inc;
    __syncthreads();
    unsigned woff = 0;
    for (int w = 0; w < (tid >> 6); ++w) woff += wave_sums[w];
    const unsigned excl = woff + inc - sum;
    if (r >= excl && r < excl + sum) {            // exactly one thread
        unsigned cum = excl;
        unsigned d   = (unsigned)(tid * 16);
        #pragma unroll
        for (int j = 0; j < 16; ++j) {
            unsigned c = sh[tid * 17 + j];
            if (cum + c > r) { d = (unsigned)(tid * 16 + j); break; }
            cum += c;
        }
        *out_digit = d;
        *out_res   = r - cum;
    }
}

// ---------------- K1: gray + histogram on float bits[31:20] + zero accum/ccnt ----------------
__global__ void k_hist(const float* __restrict__ yp, unsigned* __restrict__ hist1,
                       unsigned* __restrict__ zr, int zcount) {
    __shared__ unsigned h[NB1];
    const int tid = threadIdx.x;
    const int gtid = blockIdx.x * 256 + tid;
    if (gtid < zcount) zr[gtid] = 0;   // zero accum + ccnt (consumed only by later kernels)
    for (int i = tid; i < NB1; i += 256) h[i] = 0;
    __syncthreads();

    const int blk   = blockIdx.x;      // 4096 blocks, 256 per batch
    const int b     = blk >> 8;
    const int chunk = blk & 255;
    const long base = (long)b * 3 * NPIX;
    const int  o    = (chunk * 256 + tid) * 4;

    const float4 c0 = *(const float4*)(yp + base + o);
    const float4 c1 = *(const float4*)(yp + base + NPIX + o);
    const float4 c2 = *(const float4*)(yp + base + 2 * NPIX + o);

    atomicAdd(&h[__float_as_uint((c0.x + c1.x + c2.x) / 3.0f) >> 20], 1u);
    atomicAdd(&h[__float_as_uint((c0.y + c1.y + c2.y) / 3.0f) >> 20], 1u);
    atomicAdd(&h[__float_as_uint((c0.z + c1.z + c2.z) / 3.0f) >> 20], 1u);
    atomicAdd(&h[__float_as_uint((c0.w + c1.w + c2.w) / 3.0f) >> 20], 1u);
    __syncthreads();

    unsigned* gh = hist1 + b * NB1;
    for (int i = tid; i < NB1; i += 256) {
        unsigned v = h[i];
        if (v) atomicAdd(&gh[i], v);   // non-returning; only ~50 bins nonzero
    }
}

// ---------------- K2: tiny scan1 — one block per batch -> sel bin + residual rank ----------------
__global__ void k_scan(const unsigned* __restrict__ hist1,
                       unsigned* __restrict__ selbin, unsigned* __restrict__ resrank) {
    __shared__ unsigned sh[NB1 + (NB1 >> 4)];
    __shared__ unsigned wave_sums[4];
    const int b   = blockIdx.x;
    const int tid = threadIdx.x;
    const unsigned* hb = hist1 + b * NB1;
    for (int i = tid; i < NB1; i += 256) sh[PAD(i)] = hb[i];
    __syncthreads();
    scan4096(sh, wave_sums, tid, K_RANK, &selbin[b], &resrank[b]);
}

// ---------------- K3: loss + segmented compacted candidate collection ----------------
__global__ void k_main(const float* __restrict__ yp, const float* __restrict__ yt,
                       const unsigned* __restrict__ selbin, unsigned* __restrict__ ccnt,
                       uint2* __restrict__ cand, double* __restrict__ accum) {
    __shared__ uint2 buf[1024];
    __shared__ unsigned cnt, s_base;
    __shared__ float wsum[4];
    const int tid   = threadIdx.x;
    const int blk   = blockIdx.x;
    const int b     = blk >> 8;
    const int chunk = blk & 255;
    const int seg   = chunk >> 4;
    if (tid == 0) cnt = 0;

    const long base = (long)b * 3 * NPIX;
    const int  o    = (chunk * 256 + tid) * 4;

    const float4 p0 = *(const float4*)(yp + base + o);
    const float4 p1 = *(const float4*)(yp + base + NPIX + o);
    const float4 p2 = *(const float4*)(yp + base + 2 * NPIX + o);
    const float4 t0 = *(const float4*)(yt + base + o);
    const float4 t1 = *(const float4*)(yt + base + NPIX + o);
    const float4 t2 = *(const float4*)(yt + base + 2 * NPIX + o);
    const unsigned sel = selbin[b];
    __syncthreads();   // cnt=0 visible

    float s = 0.0f;
    {
        float g = (p0.x + p1.x + p2.x) / 3.0f;
        unsigned u = __float_as_uint(g);
        float d = fabsf(p0.x - t0.x) + fabsf(p1.x - t1.x) + fabsf(p2.x - t2.x);
        unsigned bin = u >> 20;
        s += ((bin < sel) ? 0.8f : 0.2f) * d;
        if (bin == sel) { unsigned i = atomicAdd(&cnt, 1u); buf[i] = make_uint2(u, __float_as_uint(d)); }
    }
    {
        float g = (p0.y + p1.y + p2.y) / 3.0f;
        unsigned u = __float_as_uint(g);
        float d = fabsf(p0.y - t0.y) + fabsf(p1.y - t1.y) + fabsf(p2.y - t2.y);
        unsigned bin = u >> 20;
        s += ((bin < sel) ? 0.8f : 0.2f) * d;
        if (bin == sel) { unsigned i = atomicAdd(&cnt, 1u); buf[i] = make_uint2(u, __float_as_uint(d)); }
    }
    {
        float g = (p0.z + p1.z + p2.z) / 3.0f;
        unsigned u = __float_as_uint(g);
        float d = fabsf(p0.z - t0.z) + fabsf(p1.z - t1.z) + fabsf(p2.z - t2.z);
        unsigned bin = u >> 20;
        s += ((bin < sel) ? 0.8f : 0.2f) * d;
        if (bin == sel) { unsigned i = atomicAdd(&cnt, 1u); buf[i] = make_uint2(u, __float_as_uint(d)); }
    }
    {
        float g = (p0.w + p1.w + p2.w) / 3.0f;
        unsigned u = __float_as_uint(g);
        float d = fabsf(p0.w - t0.w) + fabsf(p1.w - t1.w) + fabsf(p2.w - t2.w);
        unsigned bin = u >> 20;
        s += ((bin < sel) ? 0.8f : 0.2f) * d;
        if (bin == sel) { unsigned i = atomicAdd(&cnt, 1u); buf[i] = make_uint2(u, __float_as_uint(d)); }
    }
    __syncthreads();

    // reserve contiguous range in this chunk-group's sub-list (16 contenders max)
    if (tid == 0) s_base = cnt ? atomicAdd(&ccnt[b * NSEG + seg], cnt) : 0u;
    __syncthreads();
    const unsigned nn = cnt;
    const unsigned bs = s_base;
    uint2* dst = cand + ((long)b * NSEG + seg) * SEGCAP;
    for (unsigned i = (unsigned)tid; i < nn; i += 256) {
        unsigned slot = bs + i;
        if (slot < SEGCAP) dst[slot] = buf[i];
    }

    // block sum -> accum
    for (int off = 32; off > 0; off >>= 1) s += __shfl_down(s, off);
    if ((tid & 63) == 0) wsum[tid >> 6] = s;
    __syncthreads();
    if (tid == 0) {
        float tot = wsum[0] + wsum[1] + wsum[2] + wsum[3];
        atomicAdd(&accum[(blk & 63) * 16], (double)tot);   // 64 cache-line-spread slots
    }
}

// ---------------- K4: resolve low 20 threshold bits over segmented candidates ----------------
// Round-6 lesson: per-wave serial chain of 2 passes x 16 segments x (ccnt load ->
// cand load -> LDS atomics) = 48 us of exposed latency. Fix: preload all ccnt once,
// wave-parallel segments (serial depth 16 -> ~9 chains), and stage candidates into
// LDS during pass 1 so pass 2 never touches global memory.
__global__ void k_sel(const uint2* __restrict__ cand, const unsigned* __restrict__ resrank,
                      const unsigned* __restrict__ ccnt, double* __restrict__ accum) {
    __shared__ unsigned sh[NB1 + (NB1 >> 4)];   // 17.4 KB: mid-bin counts
    __shared__ uint2    stage[STAGE_CAP];       // 96 KB: staged candidates
    __shared__ unsigned h3[256];
    __shared__ float    sd3[256];
    __shared__ unsigned wave_sums[4];
    __shared__ unsigned segn[NSEG], sego[NSEG + 1];
    __shared__ unsigned s_bin2, s_r3, s_low;
    __shared__ float red[4];
    const int tid  = threadIdx.x;
    const int b    = blockIdx.x;
    const int wave = tid >> 6;
    const int lane = tid & 63;

    if (tid == 0) { s_bin2 = 0; s_r3 = 0; s_low = 0; }
    if (tid < NSEG) segn[tid] = min(ccnt[b * NSEG + tid], (unsigned)SEGCAP);
    const unsigned r2 = resrank[b];
    for (int i = tid; i < NB1; i += 256) sh[PAD(i)] = 0u;
    h3[tid] = 0u; sd3[tid] = 0.0f;
    __syncthreads();
    if (tid == 0) {
        unsigned acc = 0;
        #pragma unroll
        for (int s2 = 0; s2 < NSEG; ++s2) { sego[s2] = acc; acc += segn[s2]; }
        sego[NSEG] = acc;
    }
    __syncthreads();
    const unsigned T = sego[NSEG];
    const uint2* cb = cand + (long)b * NSEG * SEGCAP;

    // ---- pass 1: wave-parallel over segments; count mid-bins + stage into LDS ----
    for (int s = wave; s < NSEG; s += 4) {
        const unsigned n  = segn[s];
        const unsigned o0 = sego[s];
        const uint2* p = cb + (long)s * SEGCAP;
        for (unsigned i = (unsigned)lane * 4u; i < n; i += 256u) {
            #pragma unroll
            for (unsigned k = 0; k < 4; ++k) {
                if (i + k < n) {
                    uint2 v = p[i + k];
                    atomicAdd(&sh[PAD((v.x >> 8) & 0xFFFu)], 1u);
                    unsigned pos = o0 + i + k;
                    if (pos < STAGE_CAP) stage[pos] = v;
                }
            }
        }
    }
    __syncthreads();

    // ---- scan2 -> bin2 (bits 19:8), r3 ----
    scan4096(sh, wave_sums, tid, r2, &s_bin2, &s_r3);
    __syncthreads();
    const unsigned bin2 = s_bin2;
    const unsigned r3   = s_r3;

    // ---- pass 2 (LDS-only): S_pre partials + byte histogram within bin2 ----
    float lp = 0.0f;
    const unsigned Ts = (T < (unsigned)STAGE_CAP) ? T : (unsigned)STAGE_CAP;
    for (unsigned i = (unsigned)tid; i < Ts; i += 256u) {
        uint2 v = stage[i];
        unsigned bn = (v.x >> 8) & 0xFFFu;
        if (bn < bin2) lp += __uint_as_float(v.y);
        else if (bn == bin2) { atomicAdd(&h3[v.x & 0xFFu], 1u); atomicAdd(&sd3[v.x & 0xFFu], __uint_as_float(v.y)); }
    }
    if (T > (unsigned)STAGE_CAP) {   // correctness guard; never taken for this input
        for (int s = wave; s < NSEG; s += 4) {
            const unsigned n = segn[s], o0 = sego[s];
            const uint2* p = cb + (long)s * SEGCAP;
            for (unsigned i = (unsigned)lane; i < n; i += 64u) {
                if (o0 + i >= (unsigned)STAGE_CAP) {
                    uint2 v = p[i];
                    unsigned bn = (v.x >> 8) & 0xFFFu;
                    if (bn < bin2) lp += __uint_as_float(v.y);
                    else if (bn == bin2) { atomicAdd(&h3[v.x & 0xFFu], 1u); atomicAdd(&sd3[v.x & 0xFFu], __uint_as_float(v.y)); }
                }
            }
        }
    }
    for (int off = 32; off > 0; off >>= 1) lp += __shfl_down(lp, off);
    if (lane == 0) red[wave] = lp;
    __syncthreads();
    const float S_pre = red[0] + red[1] + red[2] + red[3];

    // ---- scan3: 256 bins, one per thread -> low byte of threshold ----
    const unsigned sum = h3[tid];
    unsigned inc = sum;
    for (int off = 1; off < 64; off <<= 1) {
        unsigned v = __shfl_up(inc, off);
        if ((tid & 63) >= off) inc += v;
    }
    if ((tid & 63) == 63) wave_sums[tid >> 6] = inc;
    __syncthreads();
    unsigned woff = 0;
    for (int w = 0; w < (tid >> 6); ++w) woff += wave_sums[w];
    const unsigned excl = woff + inc - sum;
    if (sum > 0 && r3 >= excl && r3 < excl + sum) s_low = (unsigned)tid;
    __syncthreads();
    const unsigned low = s_low;

    // ---- S_b2 = sum of d over bin2 candidates with low byte <= low ----
    float l2 = ((unsigned)tid <= low) ? sd3[tid] : 0.0f;
    for (int off = 32; off > 0; off >>= 1) l2 += __shfl_down(l2, off);
    if ((tid & 63) == 0) red[tid >> 6] = l2;
    __syncthreads();
    if (tid == 0) {
        float S_b2 = red[0] + red[1] + red[2] + red[3];
        atomicAdd(&accum[(b & 63) * 16], 0.6 * ((double)S_pre + (double)S_b2));
    }
}

__global__ void k_final(const double* __restrict__ accum, float* __restrict__ out) {
    const int tid = threadIdx.x;      // 64 threads
    double v = accum[tid * 16];
    for (int off = 32; off > 0; off >>= 1) v += __shfl_down(v, off);
    if (tid == 0) out[0] = (float)(v / 12582912.0);   // 16*3*512*512
}

extern "C" void kernel_launch(void* const* d_in, const int* in_sizes, int n_in,
                              void* d_out, int out_size, void* d_ws, size_t ws_size,
                              hipStream_t stream) {
    const float* yt = (const float*)d_in[0];   // y_true
    const float* yp = (const float*)d_in[1];   // y_pred
    float* out = (float*)d_out;
    char* ws = (char*)d_ws;

    // ws layout
    unsigned* hist1  = (unsigned*)(ws);               // 262144 B (memset)
    double*   accum  = (double*)(ws + 262144);        // 8192 B  (zeroed by k_hist zr path)
    unsigned* ccnt   = (unsigned*)(ws + 270336);      // 16*16*4 = 1024 B (zeroed by zr path)
    unsigned* zr     = (unsigned*)(ws + 262144);
    unsigned* selbin = (unsigned*)(ws + 271360);      // 64 B (written by k_scan before reads)
    unsigned* resrnk = (unsigned*)(ws + 271424);      // 64 B
    uint2*    cand   = (uint2*)(ws + (1 << 20));      // 16 * 16 * 16384 * 8 = 32 MB
    const int zcount = (8192 + 1024) / 4;             // accum + ccnt

    hipMemsetAsync(hist1, 0, 262144, stream);         // hist1 only

    k_hist <<<4096, 256, 0, stream>>>(yp, hist1, zr, zcount);
    k_scan <<<NB,   256, 0, stream>>>(hist1, selbin, resrnk);
    k_main <<<4096, 256, 0, stream>>>(yp, yt, selbin, ccnt, cand, accum);
    k_sel  <<<NB,   256, 0, stream>>>(cand, resrnk, ccnt, accum);
    k_final<<<1,    64,  0, stream>>>(accum, out);
}

// Round 8
// 163.448 us; speedup vs baseline: 1.7309x; 1.0282x over previous
//
#include <hip/hip_runtime.h>
#include <stdint.h>

#define NB 16
#define NPIX 262144            // 512*512
#define K_RANK 104856u         // int(512*512*0.4 - 1)
#define NB1 4096
#define NSEG 16                // sub-lists per batch (breaks the ccnt atomic chain)
#define SEGCAP 16384           // 8 blocks/seg * 2048 pixels: cannot overflow
#define STAGE_CAP 12288        // LDS staging capacity in k_sel (96 KB); overflow -> global path
#define PAD(i) ((i) + ((i) >> 4))

// Shared scan over 4096 padded counts in sh[]; the single thread whose range
// contains rank r writes digit + residual rank to the out pointers.
__device__ inline void scan4096(const unsigned* __restrict__ sh, unsigned* wave_sums,
                                int tid, unsigned r,
                                unsigned* out_digit, unsigned* out_res) {
    unsigned sum = 0;
    #pragma unroll
    for (int j = 0; j < 16; ++j) sum += sh[tid * 17 + j];
    unsigned inc = sum;
    for (int off = 1; off < 64; off <<= 1) {
        unsigned v = __shfl_up(inc, off);
        if ((tid & 63) >= off) inc += v;
    }
    if ((tid & 63) == 63) wave_sums[tid >> 6] = inc;
    __syncthreads();
    unsigned woff = 0;
    for (int w = 0; w < (tid >> 6); ++w) woff += wave_sums[w];
    const unsigned excl = woff + inc - sum;
    if (r >= excl && r < excl + sum) {            // exactly one thread
        unsigned cum = excl;
        unsigned d   = (unsigned)(tid * 16);
        #pragma unroll
        for (int j = 0; j < 16; ++j) {
            unsigned c = sh[tid * 17 + j];
            if (cum + c > r) { d = (unsigned)(tid * 16 + j); break; }
            cum += c;
        }
        *out_digit = d;
        *out_res   = r - cum;
    }
}

// ---------------- K1: gray + histogram on float bits[31:20] + zero accum/ccnt/fincnt ----------------
__global__ void k_hist(const float* __restrict__ yp, unsigned* __restrict__ hist1,
                       unsigned* __restrict__ zr, int zcount) {
    __shared__ unsigned h[NB1];
    const int tid = threadIdx.x;
    const int gtid = blockIdx.x * 256 + tid;
    if (gtid < zcount) zr[gtid] = 0;   // zero accum + ccnt + fincnt
    for (int i = tid; i < NB1; i += 256) h[i] = 0;
    __syncthreads();

    const int blk   = blockIdx.x;      // 4096 blocks, 256 per batch
    const int b     = blk >> 8;
    const int chunk = blk & 255;
    const long base = (long)b * 3 * NPIX;
    const int  o    = (chunk * 256 + tid) * 4;

    const float4 c0 = *(const float4*)(yp + base + o);
    const float4 c1 = *(const float4*)(yp + base + NPIX + o);
    const float4 c2 = *(const float4*)(yp + base + 2 * NPIX + o);

    atomicAdd(&h[__float_as_uint((c0.x + c1.x + c2.x) / 3.0f) >> 20], 1u);
    atomicAdd(&h[__float_as_uint((c0.y + c1.y + c2.y) / 3.0f) >> 20], 1u);
    atomicAdd(&h[__float_as_uint((c0.z + c1.z + c2.z) / 3.0f) >> 20], 1u);
    atomicAdd(&h[__float_as_uint((c0.w + c1.w + c2.w) / 3.0f) >> 20], 1u);
    __syncthreads();

    unsigned* gh = hist1 + b * NB1;
    for (int i = tid; i < NB1; i += 256) {
        unsigned v = h[i];
        if (v) atomicAdd(&gh[i], v);   // non-returning; only ~50 bins nonzero
    }
}

// ---------------- K2: tiny scan1 — one block per batch -> sel bin + residual rank ----------------
__global__ void k_scan(const unsigned* __restrict__ hist1,
                       unsigned* __restrict__ selbin, unsigned* __restrict__ resrank) {
    __shared__ unsigned sh[NB1 + (NB1 >> 4)];
    __shared__ unsigned wave_sums[4];
    const int b   = blockIdx.x;
    const int tid = threadIdx.x;
    const unsigned* hb = hist1 + b * NB1;
    for (int i = tid; i < NB1; i += 256) sh[PAD(i)] = hb[i];
    __syncthreads();
    scan4096(sh, wave_sums, tid, K_RANK, &selbin[b], &resrank[b]);
}

// ---------------- K3: loss + segmented compacted candidate collection ----------------
// Round-7 lesson: without launch_bounds the compiler allocated 16 VGPRs and
// serialized the six float4 loads into dependent phases (exposed latency).
// Force a 128-VGPR budget and process 2 quads/thread -> 12 loads in flight.
__global__ __launch_bounds__(256, 4)
void k_main(const float* __restrict__ yp, const float* __restrict__ yt,
            const unsigned* __restrict__ selbin, unsigned* __restrict__ ccnt,
            uint2* __restrict__ cand, double* __restrict__ accum) {
    __shared__ uint2 buf[2048];
    __shared__ unsigned cnt, s_base;
    __shared__ float wsum[4];
    const int tid   = threadIdx.x;
    const int blk   = blockIdx.x;      // 2048 blocks, 128 per batch
    const int b     = blk >> 7;
    const int chunk = blk & 127;
    const int seg   = chunk >> 3;      // 8 blocks per segment
    if (tid == 0) cnt = 0;

    const unsigned sel = selbin[b];    // scalar, issued first
    const long base = (long)b * 3 * NPIX;
    const int  o0   = (chunk * 512 + tid) * 4;
    const int  o1   = o0 + 1024;       // second quad (+256 threads * 4)

    const float4 pA0 = *(const float4*)(yp + base + o0);
    const float4 pA1 = *(const float4*)(yp + base + NPIX + o0);
    const float4 pA2 = *(const float4*)(yp + base + 2 * NPIX + o0);
    const float4 tA0 = *(const float4*)(yt + base + o0);
    const float4 tA1 = *(const float4*)(yt + base + NPIX + o0);
    const float4 tA2 = *(const float4*)(yt + base + 2 * NPIX + o0);
    const float4 pB0 = *(const float4*)(yp + base + o1);
    const float4 pB1 = *(const float4*)(yp + base + NPIX + o1);
    const float4 pB2 = *(const float4*)(yp + base + 2 * NPIX + o1);
    const float4 tB0 = *(const float4*)(yt + base + o1);
    const float4 tB1 = *(const float4*)(yt + base + NPIX + o1);
    const float4 tB2 = *(const float4*)(yt + base + 2 * NPIX + o1);
    __syncthreads();   // cnt=0 visible

    float s = 0.0f;
    auto proc = [&](float pr, float pg, float pb, float tr, float tg, float tb) {
        float g = (pr + pg + pb) / 3.0f;
        unsigned u = __float_as_uint(g);
        float d = fabsf(pr - tr) + fabsf(pg - tg) + fabsf(pb - tb);
        unsigned bin = u >> 20;
        s += ((bin < sel) ? 0.8f : 0.2f) * d;
        if (bin == sel) { unsigned i = atomicAdd(&cnt, 1u); buf[i] = make_uint2(u, __float_as_uint(d)); }
    };
    proc(pA0.x, pA1.x, pA2.x, tA0.x, tA1.x, tA2.x);
    proc(pA0.y, pA1.y, pA2.y, tA0.y, tA1.y, tA2.y);
    proc(pA0.z, pA1.z, pA2.z, tA0.z, tA1.z, tA2.z);
    proc(pA0.w, pA1.w, pA2.w, tA0.w, tA1.w, tA2.w);
    proc(pB0.x, pB1.x, pB2.x, tB0.x, tB1.x, tB2.x);
    proc(pB0.y, pB1.y, pB2.y, tB0.y, tB1.y, tB2.y);
    proc(pB0.z, pB1.z, pB2.z, tB0.z, tB1.z, tB2.z);
    proc(pB0.w, pB1.w, pB2.w, tB0.w, tB1.w, tB2.w);
    __syncthreads();

    // reserve contiguous range in this chunk-group's sub-list (8 contenders max)
    if (tid == 0) s_base = cnt ? atomicAdd(&ccnt[b * NSEG + seg], cnt) : 0u;
    __syncthreads();
    const unsigned nn = cnt;
    const unsigned bs = s_base;
    uint2* dst = cand + ((long)b * NSEG + seg) * SEGCAP;
    for (unsigned i = (unsigned)tid; i < nn; i += 256) {
        unsigned slot = bs + i;
        if (slot < SEGCAP) dst[slot] = buf[i];
    }

    // block sum -> accum
    for (int off = 32; off > 0; off >>= 1) s += __shfl_down(s, off);
    if ((tid & 63) == 0) wsum[tid >> 6] = s;
    __syncthreads();
    if (tid == 0) {
        float tot = wsum[0] + wsum[1] + wsum[2] + wsum[3];
        atomicAdd(&accum[(blk & 63) * 16], (double)tot);   // 64 cache-line-spread slots
    }
}

// ---------------- K4: resolve low 20 threshold bits + fused final reduce ----------------
// 16-block last-done handshake (16 device fences is bounded, unlike round-1's 4096).
__global__ void k_sel(const uint2* __restrict__ cand, const unsigned* __restrict__ resrank,
                      const unsigned* __restrict__ ccnt, double* __restrict__ accum,
                      unsigned* __restrict__ fincnt, float* __restrict__ out) {
    __shared__ unsigned sh[NB1 + (NB1 >> 4)];   // 17.4 KB: mid-bin counts
    __shared__ uint2    stage[STAGE_CAP];       // 96 KB: staged candidates
    __shared__ unsigned h3[256];
    __shared__ float    sd3[256];
    __shared__ unsigned wave_sums[4];
    __shared__ unsigned segn[NSEG], sego[NSEG + 1];
    __shared__ unsigned s_bin2, s_r3, s_low, s_last;
    __shared__ float red[4];
    const int tid  = threadIdx.x;
    const int b    = blockIdx.x;
    const int wave = tid >> 6;
    const int lane = tid & 63;

    if (tid == 0) { s_bin2 = 0; s_r3 = 0; s_low = 0; }
    if (tid < NSEG) segn[tid] = min(ccnt[b * NSEG + tid], (unsigned)SEGCAP);
    const unsigned r2 = resrank[b];
    for (int i = tid; i < NB1; i += 256) sh[PAD(i)] = 0u;
    h3[tid] = 0u; sd3[tid] = 0.0f;
    __syncthreads();
    if (tid == 0) {
        unsigned acc = 0;
        #pragma unroll
        for (int s2 = 0; s2 < NSEG; ++s2) { sego[s2] = acc; acc += segn[s2]; }
        sego[NSEG] = acc;
    }
    __syncthreads();
    const unsigned T = sego[NSEG];
    const uint2* cb = cand + (long)b * NSEG * SEGCAP;

    // ---- pass 1: wave-parallel over segments; count mid-bins + stage into LDS ----
    for (int s = wave; s < NSEG; s += 4) {
        const unsigned n  = segn[s];
        const unsigned o0 = sego[s];
        const uint2* p = cb + (long)s * SEGCAP;
        for (unsigned i = (unsigned)lane * 4u; i < n; i += 256u) {
            #pragma unroll
            for (unsigned k = 0; k < 4; ++k) {
                if (i + k < n) {
                    uint2 v = p[i + k];
                    atomicAdd(&sh[PAD((v.x >> 8) & 0xFFFu)], 1u);
                    unsigned pos = o0 + i + k;
                    if (pos < STAGE_CAP) stage[pos] = v;
                }
            }
        }
    }
    __syncthreads();

    // ---- scan2 -> bin2 (bits 19:8), r3 ----
    scan4096(sh, wave_sums, tid, r2, &s_bin2, &s_r3);
    __syncthreads();
    const unsigned bin2 = s_bin2;
    const unsigned r3   = s_r3;

    // ---- pass 2 (LDS-only): S_pre partials + byte histogram within bin2 ----
    float lp = 0.0f;
    const unsigned Ts = (T < (unsigned)STAGE_CAP) ? T : (unsigned)STAGE_CAP;
    for (unsigned i = (unsigned)tid; i < Ts; i += 256u) {
        uint2 v = stage[i];
        unsigned bn = (v.x >> 8) & 0xFFFu;
        if (bn < bin2) lp += __uint_as_float(v.y);
        else if (bn == bin2) { atomicAdd(&h3[v.x & 0xFFu], 1u); atomicAdd(&sd3[v.x & 0xFFu], __uint_as_float(v.y)); }
    }
    if (T > (unsigned)STAGE_CAP) {   // correctness guard; never taken for this input
        for (int s = wave; s < NSEG; s += 4) {
            const unsigned n = segn[s], o0 = sego[s];
            const uint2* p = cb + (long)s * SEGCAP;
            for (unsigned i = (unsigned)lane; i < n; i += 64u) {
                if (o0 + i >= (unsigned)STAGE_CAP) {
                    uint2 v = p[i];
                    unsigned bn = (v.x >> 8) & 0xFFFu;
                    if (bn < bin2) lp += __uint_as_float(v.y);
                    else if (bn == bin2) { atomicAdd(&h3[v.x & 0xFFu], 1u); atomicAdd(&sd3[v.x & 0xFFu], __uint_as_float(v.y)); }
                }
            }
        }
    }
    for (int off = 32; off > 0; off >>= 1) lp += __shfl_down(lp, off);
    if (lane == 0) red[wave] = lp;
    __syncthreads();
    const float S_pre = red[0] + red[1] + red[2] + red[3];

    // ---- scan3: 256 bins, one per thread -> low byte of threshold ----
    const unsigned sum = h3[tid];
    unsigned inc = sum;
    for (int off = 1; off < 64; off <<= 1) {
        unsigned v = __shfl_up(inc, off);
        if ((tid & 63) >= off) inc += v;
    }
    if ((tid & 63) == 63) wave_sums[tid >> 6] = inc;
    __syncthreads();
    unsigned woff = 0;
    for (int w = 0; w < (tid >> 6); ++w) woff += wave_sums[w];
    const unsigned excl = woff + inc - sum;
    if (sum > 0 && r3 >= excl && r3 < excl + sum) s_low = (unsigned)tid;
    __syncthreads();
    const unsigned low = s_low;

    // ---- S_b2 = sum of d over bin2 candidates with low byte <= low ----
    float l2 = ((unsigned)tid <= low) ? sd3[tid] : 0.0f;
    for (int off = 32; off > 0; off >>= 1) l2 += __shfl_down(l2, off);
    if ((tid & 63) == 0) red[tid >> 6] = l2;
    __syncthreads();
    if (tid == 0) {
        float S_b2 = red[0] + red[1] + red[2] + red[3];
        atomicAdd(&accum[(b & 63) * 16], 0.6 * ((double)S_pre + (double)S_b2));
        __threadfence();                         // publish before signaling
        unsigned done = atomicAdd(fincnt, 1u);
        s_last = (done == NB - 1) ? 1u : 0u;
    }
    __syncthreads();

    // ---- last block: final reduction over the 64 accum slots ----
    if (s_last && tid < 64) {
        __threadfence();                          // acquire side
        double v = atomicAdd(&accum[tid * 16], 0.0);   // device-scope coherent read
        for (int off = 32; off > 0; off >>= 1) v += __shfl_down(v, off);
        if (tid == 0) out[0] = (float)(v / 12582912.0);   // 16*3*512*512
    }
}

extern "C" void kernel_launch(void* const* d_in, const int* in_sizes, int n_in,
                              void* d_out, int out_size, void* d_ws, size_t ws_size,
                              hipStream_t stream) {
    const float* yt = (const float*)d_in[0];   // y_true
    const float* yp = (const float*)d_in[1];   // y_pred
    float* out = (float*)d_out;
    char* ws = (char*)d_ws;

    // ws layout
    unsigned* hist1  = (unsigned*)(ws);               // 262144 B (memset)
    double*   accum  = (double*)(ws + 262144);        // 8192 B  (zeroed by k_hist zr path)
    unsigned* ccnt   = (unsigned*)(ws + 270336);      // 16*16*4 = 1024 B (zeroed by zr path)
    unsigned* fincnt = (unsigned*)(ws + 271360);      // 64 B    (zeroed by zr path)
    unsigned* zr     = (unsigned*)(ws + 262144);
    unsigned* selbin = (unsigned*)(ws + 271424);      // 64 B (written by k_scan before reads)
    unsigned* resrnk = (unsigned*)(ws + 271488);      // 64 B
    uint2*    cand   = (uint2*)(ws + (1 << 20));      // 16 * 16 * 16384 * 8 = 32 MB
    const int zcount = (8192 + 1024 + 64) / 4;        // accum + ccnt + fincnt

    hipMemsetAsync(hist1, 0, 262144, stream);         // hist1 only

    k_hist <<<4096, 256, 0, stream>>>(yp, hist1, zr, zcount);
    k_scan <<<NB,   256, 0, stream>>>(hist1, selbin, resrnk);
    k_main <<<2048, 256, 0, stream>>>(yp, yt, selbin, ccnt, cand, accum);
    k_sel  <<<NB,   256, 0, stream>>>(cand, resrnk, ccnt, accum, fincnt, out);
}